// Round 1
// baseline (424.104 us; speedup 1.0000x reference)
//
#include <hip/hip_runtime.h>

#define IN_F 4096
#define OUT_F 4096
#define RANK 64
#define NROWS 8192

// ---------------- P1: G = f0*f1 [256x64], H = f4*f5 [64x256] ----------------
__global__ __launch_bounds__(256) void tt_p1(
    const float* __restrict__ f0, const float* __restrict__ f1,
    const float* __restrict__ f4, const float* __restrict__ f5,
    float* __restrict__ G, float* __restrict__ H) {
  int g = blockIdx.x * 256 + threadIdx.x;  // 32768 total
  if (g < 16384) {
    // G[(i1*16+i2)*64 + r2] = sum_r1 f0[i1,r1] * f1[r1,i2,r2]
    int i12 = g >> 6, r2 = g & 63;
    int i1 = i12 >> 4, i2 = i12 & 15;
    const float* a = f0 + i1 * 64;
    const float* b = f1 + i2 * 64 + r2;
    float s = 0.f;
#pragma unroll
    for (int r1 = 0; r1 < 64; ++r1) s += a[r1] * b[r1 * 1024];
    G[g] = s;
  } else {
    // H[r4*256 + i5*16+i6] = sum_r5 f4[r4,i5,r5] * f5[r5,i6]
    int h = g - 16384;
    int r4 = h >> 8, i56 = h & 255;
    int i5 = i56 >> 4, i6 = i56 & 15;
    const float* a = f4 + r4 * 1024 + i5 * 64;
    const float* b = f5 + i6;
    float s = 0.f;
#pragma unroll
    for (int r5 = 0; r5 < 64; ++r5) s += a[r5] * b[r5 * 16];
    H[h] = s;
  }
}

// ---------------- P2: L[4096x64] = G*f2, R[64x4096] = f3*H ----------------
__global__ __launch_bounds__(256) void tt_p2(
    const float* __restrict__ f2, const float* __restrict__ f3,
    const float* __restrict__ G, const float* __restrict__ H,
    float* __restrict__ L, float* __restrict__ R) {
  int g = blockIdx.x * 256 + threadIdx.x;  // 524288 total
  if (g < 262144) {
    // L[row*64+r3] = sum_r2 G[(row>>4)*64+r2] * f2[r2, row&15, r3]
    int row = g >> 6, r3 = g & 63;
    int i12 = row >> 4, i3 = row & 15;
    const float* a = G + i12 * 64;
    const float* b = f2 + i3 * 64 + r3;
    float s = 0.f;
#pragma unroll
    for (int r2 = 0; r2 < 64; ++r2) s += a[r2] * b[r2 * 1024];
    L[g] = s;
  } else {
    // R[r3*4096+col] = sum_r4 f3[r3, col>>8, r4] * H[r4*256 + (col&255)]
    int h = g - 262144;
    int r3 = h >> 12, col = h & 4095;
    int i4 = col >> 8, i56 = col & 255;
    const float* a = f3 + r3 * 1024 + i4 * 64;
    const float* b = H + i56;
    float s = 0.f;
#pragma unroll
    for (int r4 = 0; r4 < 64; ++r4) s += a[r4] * b[r4 * 256];
    R[h] = s;
  }
}

// ---------------- C: tpart[s] = x[.,kslice] @ L[kslice,.]  (M=8192,N=64) ----
// block = 256 threads, 64 rows/block, thread tile 4 rows x 4 cols, no LDS.
__global__ __launch_bounds__(256) void tt_xl(
    const float* __restrict__ x, const float* __restrict__ L,
    float* __restrict__ tpart, int KC) {
  int tid = threadIdx.x;
  int cg = tid & 15, rg = tid >> 4;
  int c0 = cg * 4;
  long r0 = (long)blockIdx.x * 64 + rg * 4;
  int k0 = blockIdx.y * KC;

  float acc[4][4] = {};
  const float* xp = x + r0 * IN_F + k0;
  const float* lp = L + (long)k0 * 64 + c0;

  for (int k = 0; k < KC; k += 4) {
    float4 xv[4];
#pragma unroll
    for (int i = 0; i < 4; ++i)
      xv[i] = *reinterpret_cast<const float4*>(xp + (long)i * IN_F + k);
#pragma unroll
    for (int kk = 0; kk < 4; ++kk) {
      float4 lv = *reinterpret_cast<const float4*>(lp + (k + kk) * 64);
#pragma unroll
      for (int i = 0; i < 4; ++i) {
        float xs = (kk == 0) ? xv[i].x : (kk == 1) ? xv[i].y
                 : (kk == 2) ? xv[i].z : xv[i].w;
        acc[i][0] += xs * lv.x;
        acc[i][1] += xs * lv.y;
        acc[i][2] += xs * lv.z;
        acc[i][3] += xs * lv.w;
      }
    }
  }
  float* op = tpart + (size_t)blockIdx.y * (NROWS * 64) + r0 * 64 + c0;
#pragma unroll
  for (int i = 0; i < 4; ++i) {
    float4 v = make_float4(acc[i][0], acc[i][1], acc[i][2], acc[i][3]);
    *reinterpret_cast<float4*>(op + i * 64) = v;
  }
}

// ---------------- C2: t = sum_s tpart[s] ----------------
__global__ __launch_bounds__(256) void tt_red(
    const float* __restrict__ tpart, float* __restrict__ t, int splitk) {
  int g = blockIdx.x * 256 + threadIdx.x;  // float4 index, 131072 total
  float4 s = make_float4(0.f, 0.f, 0.f, 0.f);
  const float4* p = reinterpret_cast<const float4*>(tpart) + g;
  for (int i = 0; i < splitk; ++i) {
    float4 v = p[(size_t)i * (NROWS * 16)];
    s.x += v.x; s.y += v.y; s.z += v.z; s.w += v.w;
  }
  reinterpret_cast<float4*>(t)[g] = s;
}

// ---------------- D: y = t @ R + bias  (M=8192, N=4096, K=64) ----------------
// block = 256 threads, tile 128 rows x 128 cols, thread tile 8x8.
__global__ __launch_bounds__(256) void tt_tr(
    const float* __restrict__ t, const float* __restrict__ R,
    const float* __restrict__ bias, float* __restrict__ y) {
  __shared__ float tS[128][66];  // [row][k], +2 pad
  int tid = threadIdx.x;
  long rb0 = (long)blockIdx.y * 128;
  int cb0 = blockIdx.x * 128;

  // stage t tile: 128 rows x 64 k = 8192 floats; 8 float4 per thread
#pragma unroll
  for (int p = 0; p < 8; ++p) {
    int f = tid + p * 256;
    int row = f >> 4, kq = f & 15;
    float4 v = *reinterpret_cast<const float4*>(t + (rb0 + row) * 64 + kq * 4);
    tS[row][kq * 4 + 0] = v.x;
    tS[row][kq * 4 + 1] = v.y;
    tS[row][kq * 4 + 2] = v.z;
    tS[row][kq * 4 + 3] = v.w;
  }
  __syncthreads();

  int cg = tid & 15, rg = tid >> 4;
  int c0 = cb0 + cg * 8;
  int r0 = rg * 8;
  float acc[8][8] = {};
  const float* rp = R + c0;

#pragma unroll 4
  for (int k = 0; k < 64; ++k) {
    float tv[8];
#pragma unroll
    for (int i = 0; i < 8; ++i) tv[i] = tS[r0 + i][k];
    float4 ra = *reinterpret_cast<const float4*>(rp + (size_t)k * OUT_F);
    float4 rb = *reinterpret_cast<const float4*>(rp + (size_t)k * OUT_F + 4);
    float rv[8] = {ra.x, ra.y, ra.z, ra.w, rb.x, rb.y, rb.z, rb.w};
#pragma unroll
    for (int i = 0; i < 8; ++i)
#pragma unroll
      for (int j = 0; j < 8; ++j) acc[i][j] += tv[i] * rv[j];
  }

  float4 ba = *reinterpret_cast<const float4*>(bias + c0);
  float4 bb = *reinterpret_cast<const float4*>(bias + c0 + 4);
  float bv[8] = {ba.x, ba.y, ba.z, ba.w, bb.x, bb.y, bb.z, bb.w};
#pragma unroll
  for (int i = 0; i < 8; ++i) {
    float4 o0, o1;
    o0.x = acc[i][0] + bv[0]; o0.y = acc[i][1] + bv[1];
    o0.z = acc[i][2] + bv[2]; o0.w = acc[i][3] + bv[3];
    o1.x = acc[i][4] + bv[4]; o1.y = acc[i][5] + bv[5];
    o1.z = acc[i][6] + bv[6]; o1.w = acc[i][7] + bv[7];
    float* yp = y + (rb0 + r0 + i) * (long)OUT_F + c0;
    *reinterpret_cast<float4*>(yp) = o0;
    *reinterpret_cast<float4*>(yp + 4) = o1;
  }
}

extern "C" void kernel_launch(void* const* d_in, const int* in_sizes, int n_in,
                              void* d_out, int out_size, void* d_ws,
                              size_t ws_size, hipStream_t stream) {
  (void)in_sizes; (void)n_in; (void)out_size;
  const float* x    = (const float*)d_in[0];
  const float* f0   = (const float*)d_in[1];
  const float* f1   = (const float*)d_in[2];
  const float* f2   = (const float*)d_in[3];
  const float* f3   = (const float*)d_in[4];
  const float* f4   = (const float*)d_in[5];
  const float* f5   = (const float*)d_in[6];
  const float* bias = (const float*)d_in[7];
  float* y = (float*)d_out;

  // workspace layout (floats)
  float* ws = (float*)d_ws;
  float* L     = ws;                 // 262144
  float* R     = ws + 262144;        // 262144
  float* G     = ws + 524288;        // 16384
  float* H     = ws + 540672;        // 16384
  float* t     = ws + 557056;        // 524288
  float* tpart = ws + 1081344;       // splitk * 524288

  int splitk = 8;
  while (splitk > 1 &&
         (size_t)(1081344 + (size_t)splitk * 524288) * 4 > ws_size)
    splitk >>= 1;

  tt_p1<<<128, 256, 0, stream>>>(f0, f1, f4, f5, G, H);
  tt_p2<<<2048, 256, 0, stream>>>(f2, f3, G, H, L, R);

  if (splitk > 1) {
    int KC = 4096 / splitk;
    tt_xl<<<dim3(128, splitk), 256, 0, stream>>>(x, L, tpart, KC);
    tt_red<<<512, 256, 0, stream>>>(tpart, t, splitk);
  } else {
    tt_xl<<<dim3(128, 1), 256, 0, stream>>>(x, L, t, 4096);
  }

  // grid: x = col blocks (32), y = row blocks (64)
  tt_tr<<<dim3(32, 64), 256, 0, stream>>>(t, R, bias, y);
}

// Round 2
// 415.738 us; speedup vs baseline: 1.0201x; 1.0201x over previous
//
#include <hip/hip_runtime.h>

#define IN_F 4096
#define OUT_F 4096
#define NROWS 8192

// ---------------- P1: G = f0*f1 [256x64], H = f4*f5 [64x256] ----------------
__global__ __launch_bounds__(256) void tt_p1(
    const float* __restrict__ f0, const float* __restrict__ f1,
    const float* __restrict__ f4, const float* __restrict__ f5,
    float* __restrict__ G, float* __restrict__ H) {
  int g = blockIdx.x * 256 + threadIdx.x;  // 32768 total
  if (g < 16384) {
    int i12 = g >> 6, r2 = g & 63;
    int i1 = i12 >> 4, i2 = i12 & 15;
    const float* a = f0 + i1 * 64;
    const float* b = f1 + i2 * 64 + r2;
    float s = 0.f;
#pragma unroll
    for (int r1 = 0; r1 < 64; ++r1) s += a[r1] * b[r1 * 1024];
    G[g] = s;
  } else {
    int h = g - 16384;
    int r4 = h >> 8, i56 = h & 255;
    int i5 = i56 >> 4, i6 = i56 & 15;
    const float* a = f4 + r4 * 1024 + i5 * 64;
    const float* b = f5 + i6;
    float s = 0.f;
#pragma unroll
    for (int r5 = 0; r5 < 64; ++r5) s += a[r5] * b[r5 * 16];
    H[h] = s;
  }
}

// ---------------- P2: L[4096x64] = G*f2, R[64x4096] = f3*H ----------------
__global__ __launch_bounds__(256) void tt_p2(
    const float* __restrict__ f2, const float* __restrict__ f3,
    const float* __restrict__ G, const float* __restrict__ H,
    float* __restrict__ L, float* __restrict__ R) {
  int g = blockIdx.x * 256 + threadIdx.x;  // 524288 total
  if (g < 262144) {
    int row = g >> 6, r3 = g & 63;
    int i12 = row >> 4, i3 = row & 15;
    const float* a = G + i12 * 64;
    const float* b = f2 + i3 * 64 + r3;
    float s = 0.f;
#pragma unroll
    for (int r2 = 0; r2 < 64; ++r2) s += a[r2] * b[r2 * 1024];
    L[g] = s;
  } else {
    int h = g - 262144;
    int r3 = h >> 12, col = h & 4095;
    int i4 = col >> 8, i56 = col & 255;
    const float* a = f3 + r3 * 1024 + i4 * 64;
    const float* b = H + i56;
    float s = 0.f;
#pragma unroll
    for (int r4 = 0; r4 < 64; ++r4) s += a[r4] * b[r4 * 256];
    R[h] = s;
  }
}

// ---------------- C: tpart = x @ L  (M=8192, N=64, split-K) ----------------
// block 256 thr, 128 rows x 64 cols tile. LDS-staged x (coalesced), reg
// prefetch of next chunk. Thread tile 8 rows (stride 16) x 4 cols.
__global__ __launch_bounds__(256) void tt_xl(
    const float* __restrict__ x, const float* __restrict__ L,
    float* __restrict__ tpart, int KC) {
  __shared__ float xS[128 * 36];  // pitch 36: rg-stride bank offset 4
  int tid = threadIdx.x;
  int cg = tid & 15, rg = tid >> 4;
  int c0 = cg * 4;
  long rb0 = (long)blockIdx.x * 128;
  int k0 = blockIdx.y * KC;
  int NC = KC >> 5;  // 32-k chunks

  float acc[8][4] = {};
  float4 xr[4];

  const float* xb = x + rb0 * IN_F + k0;
#pragma unroll
  for (int p = 0; p < 4; ++p) {
    int f = tid + p * 256;
    xr[p] = *reinterpret_cast<const float4*>(
        xb + (long)(f >> 3) * IN_F + (f & 7) * 4);
  }

  for (int c = 0; c < NC; ++c) {
    if (c) __syncthreads();
#pragma unroll
    for (int p = 0; p < 4; ++p) {
      int f = tid + p * 256;
      *reinterpret_cast<float4*>(&xS[(f >> 3) * 36 + (f & 7) * 4]) = xr[p];
    }
    __syncthreads();
    if (c + 1 < NC) {
      const float* xn = xb + (c + 1) * 32;
#pragma unroll
      for (int p = 0; p < 4; ++p) {
        int f = tid + p * 256;
        xr[p] = *reinterpret_cast<const float4*>(
            xn + (long)(f >> 3) * IN_F + (f & 7) * 4);
      }
    }
    const float* lb = L + (long)(k0 + c * 32) * 64 + c0;
#pragma unroll
    for (int kk = 0; kk < 32; kk += 4) {
      float4 xv[8];
#pragma unroll
      for (int i = 0; i < 8; ++i)
        xv[i] = *reinterpret_cast<const float4*>(&xS[(rg + 16 * i) * 36 + kk]);
#pragma unroll
      for (int q = 0; q < 4; ++q) {
        float4 lv = *reinterpret_cast<const float4*>(lb + (kk + q) * 64);
#pragma unroll
        for (int i = 0; i < 8; ++i) {
          float xs = q == 0 ? xv[i].x : q == 1 ? xv[i].y
                   : q == 2 ? xv[i].z : xv[i].w;
          acc[i][0] += xs * lv.x;
          acc[i][1] += xs * lv.y;
          acc[i][2] += xs * lv.z;
          acc[i][3] += xs * lv.w;
        }
      }
    }
  }
  float* op = tpart + (size_t)blockIdx.y * ((size_t)NROWS * 64);
#pragma unroll
  for (int i = 0; i < 8; ++i)
    *reinterpret_cast<float4*>(op + (rb0 + rg + 16 * i) * 64 + c0) =
        make_float4(acc[i][0], acc[i][1], acc[i][2], acc[i][3]);
}

// ---------------- C2: t = sum_s tpart[s] ----------------
__global__ __launch_bounds__(256) void tt_red(
    const float* __restrict__ tpart, float* __restrict__ t, int splitk) {
  int g = blockIdx.x * 256 + threadIdx.x;  // float4 index, 131072 total
  float4 s = make_float4(0.f, 0.f, 0.f, 0.f);
  const float4* p = reinterpret_cast<const float4*>(tpart) + g;
  for (int i = 0; i < splitk; ++i) {
    float4 v = p[(size_t)i * (NROWS * 16)];
    s.x += v.x; s.y += v.y; s.z += v.z; s.w += v.w;
  }
  reinterpret_cast<float4*>(t)[g] = s;
}

// ---------------- D: y = t @ R + bias (M=8192, N=4096, K=64) ----------------
// 128x128 tile, both operands staged in LDS once, 8x8 thread tile with
// col-quads at cg*4 and 64+cg*4 (bank-conflict-free rS reads).
__global__ __launch_bounds__(256) void tt_tr(
    const float* __restrict__ t, const float* __restrict__ R,
    const float* __restrict__ bias, float* __restrict__ y) {
  __shared__ float tS[128 * 68];  // [row][k] pitch 68
  __shared__ float rS[64 * 128];  // [k][col]
  int tid = threadIdx.x;
  long rb0 = (long)blockIdx.y * 128;
  int cb0 = blockIdx.x * 128;

#pragma unroll
  for (int p = 0; p < 8; ++p) {
    int f = tid + p * 256;
    int row = f >> 4, kq = f & 15;
    *reinterpret_cast<float4*>(&tS[row * 68 + kq * 4]) =
        *reinterpret_cast<const float4*>(t + (rb0 + row) * 64 + kq * 4);
  }
#pragma unroll
  for (int p = 0; p < 8; ++p) {
    int f = tid + p * 256;
    int k = f >> 5, c4 = f & 31;
    *reinterpret_cast<float4*>(&rS[k * 128 + c4 * 4]) =
        *reinterpret_cast<const float4*>(R + (size_t)k * OUT_F + cb0 + c4 * 4);
  }
  __syncthreads();

  int cg = tid & 15, rg = tid >> 4;
  int ca = cg * 4, cb = 64 + cg * 4;
  float acc[8][8] = {};
#pragma unroll
  for (int k = 0; k < 64; k += 4) {
    float4 tv[8];
#pragma unroll
    for (int i = 0; i < 8; ++i)
      tv[i] = *reinterpret_cast<const float4*>(&tS[(rg + 16 * i) * 68 + k]);
#pragma unroll
    for (int q = 0; q < 4; ++q) {
      float4 r0 = *reinterpret_cast<const float4*>(&rS[(k + q) * 128 + ca]);
      float4 r1 = *reinterpret_cast<const float4*>(&rS[(k + q) * 128 + cb]);
#pragma unroll
      for (int i = 0; i < 8; ++i) {
        float ts = q == 0 ? tv[i].x : q == 1 ? tv[i].y
                 : q == 2 ? tv[i].z : tv[i].w;
        acc[i][0] += ts * r0.x; acc[i][1] += ts * r0.y;
        acc[i][2] += ts * r0.z; acc[i][3] += ts * r0.w;
        acc[i][4] += ts * r1.x; acc[i][5] += ts * r1.y;
        acc[i][6] += ts * r1.z; acc[i][7] += ts * r1.w;
      }
    }
  }
  float4 b0 = *reinterpret_cast<const float4*>(bias + cb0 + ca);
  float4 b1 = *reinterpret_cast<const float4*>(bias + cb0 + cb);
#pragma unroll
  for (int i = 0; i < 8; ++i) {
    float* yp = y + (rb0 + rg + 16 * i) * (long)OUT_F + cb0;
    *reinterpret_cast<float4*>(yp + ca) = make_float4(
        acc[i][0] + b0.x, acc[i][1] + b0.y, acc[i][2] + b0.z, acc[i][3] + b0.w);
    *reinterpret_cast<float4*>(yp + cb) = make_float4(
        acc[i][4] + b1.x, acc[i][5] + b1.y, acc[i][6] + b1.z, acc[i][7] + b1.w);
  }
}

extern "C" void kernel_launch(void* const* d_in, const int* in_sizes, int n_in,
                              void* d_out, int out_size, void* d_ws,
                              size_t ws_size, hipStream_t stream) {
  (void)in_sizes; (void)n_in; (void)out_size;
  const float* x    = (const float*)d_in[0];
  const float* f0   = (const float*)d_in[1];
  const float* f1   = (const float*)d_in[2];
  const float* f2   = (const float*)d_in[3];
  const float* f3   = (const float*)d_in[4];
  const float* f4   = (const float*)d_in[5];
  const float* f5   = (const float*)d_in[6];
  const float* bias = (const float*)d_in[7];
  float* y = (float*)d_out;

  float* ws = (float*)d_ws;
  float* L     = ws;                 // 262144
  float* R     = ws + 262144;        // 262144
  float* G     = ws + 524288;        // 16384
  float* H     = ws + 540672;        // 16384
  float* t     = ws + 557056;        // 524288
  float* tpart = ws + 1081344;       // splitk * 524288

  int splitk = 16;
  while (splitk > 1 &&
         (size_t)(1081344 + (size_t)splitk * 524288) * 4 > ws_size)
    splitk >>= 1;

  tt_p1<<<128, 256, 0, stream>>>(f0, f1, f4, f5, G, H);
  tt_p2<<<2048, 256, 0, stream>>>(f2, f3, G, H, L, R);

  int KC = 4096 / splitk;
  if (splitk > 1) {
    tt_xl<<<dim3(64, splitk), 256, 0, stream>>>(x, L, tpart, KC);
    tt_red<<<512, 256, 0, stream>>>(tpart, t, splitk);
  } else {
    tt_xl<<<dim3(64, 1), 256, 0, stream>>>(x, L, t, 4096);
  }

  tt_tr<<<dim3(32, 64), 256, 0, stream>>>(t, R, bias, y);
}

// Round 3
// 373.735 us; speedup vs baseline: 1.1348x; 1.1124x over previous
//
#include <hip/hip_runtime.h>

#define IN_F 4096
#define OUT_F 4096
#define NROWS 8192

// ---------------- P1: G = f0*f1 [256x64], H = f4*f5 [64x256] ----------------
__global__ __launch_bounds__(256) void tt_p1(
    const float* __restrict__ f0, const float* __restrict__ f1,
    const float* __restrict__ f4, const float* __restrict__ f5,
    float* __restrict__ G, float* __restrict__ H) {
  int g = blockIdx.x * 256 + threadIdx.x;  // 32768 total
  if (g < 16384) {
    int i12 = g >> 6, r2 = g & 63;
    int i1 = i12 >> 4, i2 = i12 & 15;
    const float* a = f0 + i1 * 64;
    const float* b = f1 + i2 * 64 + r2;
    float s = 0.f;
#pragma unroll
    for (int r1 = 0; r1 < 64; ++r1) s += a[r1] * b[r1 * 1024];
    G[g] = s;
  } else {
    int h = g - 16384;
    int r4 = h >> 8, i56 = h & 255;
    int i5 = i56 >> 4, i6 = i56 & 15;
    const float* a = f4 + r4 * 1024 + i5 * 64;
    const float* b = f5 + i6;
    float s = 0.f;
#pragma unroll
    for (int r5 = 0; r5 < 64; ++r5) s += a[r5] * b[r5 * 16];
    H[h] = s;
  }
}

// ---------------- P2: L[4096x64] = G*f2, R[64x4096] = f3*H ----------------
__global__ __launch_bounds__(256) void tt_p2(
    const float* __restrict__ f2, const float* __restrict__ f3,
    const float* __restrict__ G, const float* __restrict__ H,
    float* __restrict__ L, float* __restrict__ R) {
  int g = blockIdx.x * 256 + threadIdx.x;  // 524288 total
  if (g < 262144) {
    int row = g >> 6, r3 = g & 63;
    int i12 = row >> 4, i3 = row & 15;
    const float* a = G + i12 * 64;
    const float* b = f2 + i3 * 64 + r3;
    float s = 0.f;
#pragma unroll
    for (int r2 = 0; r2 < 64; ++r2) s += a[r2] * b[r2 * 1024];
    L[g] = s;
  } else {
    int h = g - 262144;
    int r3 = h >> 12, col = h & 4095;
    int i4 = col >> 8, i56 = col & 255;
    const float* a = f3 + r3 * 1024 + i4 * 64;
    const float* b = H + i56;
    float s = 0.f;
#pragma unroll
    for (int r4 = 0; r4 < 64; ++r4) s += a[r4] * b[r4 * 256];
    R[h] = s;
  }
}

// ---------------- C: tpart = x @ L  (M=8192, N=64, split-K) ----------------
// 128 rows x 64 cols per block. BOTH operands LDS-staged per 32-k chunk,
// register double-buffer prefetch. Pure-LDS inner loop.
__global__ __launch_bounds__(256) void tt_xl(
    const float* __restrict__ x, const float* __restrict__ L,
    float* __restrict__ tpart, int KC) {
  __shared__ float xS[128 * 36];  // [row][k] pitch 36
  __shared__ float lS[32 * 64];   // [k][col] linear
  int tid = threadIdx.x;
  int cg = tid & 15, rg = tid >> 4;
  int c0 = cg * 4;
  long rb0 = (long)blockIdx.x * 128;
  int k0 = blockIdx.y * KC;
  int NC = KC >> 5;

  float acc[8][4] = {};
  float4 xr[4], lr[2];

  const float* xb = x + rb0 * IN_F + k0;
#pragma unroll
  for (int p = 0; p < 4; ++p) {
    int f = tid + p * 256;
    xr[p] = *reinterpret_cast<const float4*>(
        xb + (long)(f >> 3) * IN_F + (f & 7) * 4);
  }
#pragma unroll
  for (int p = 0; p < 2; ++p)
    lr[p] = reinterpret_cast<const float4*>(L + (long)k0 * 64)[tid + p * 256];

  for (int c = 0; c < NC; ++c) {
    if (c) __syncthreads();
#pragma unroll
    for (int p = 0; p < 4; ++p) {
      int f = tid + p * 256;
      *reinterpret_cast<float4*>(&xS[(f >> 3) * 36 + (f & 7) * 4]) = xr[p];
    }
#pragma unroll
    for (int p = 0; p < 2; ++p)
      reinterpret_cast<float4*>(lS)[tid + p * 256] = lr[p];
    __syncthreads();
    if (c + 1 < NC) {
      const float* xn = xb + (c + 1) * 32;
#pragma unroll
      for (int p = 0; p < 4; ++p) {
        int f = tid + p * 256;
        xr[p] = *reinterpret_cast<const float4*>(
            xn + (long)(f >> 3) * IN_F + (f & 7) * 4);
      }
      const float* ln = L + (long)(k0 + (c + 1) * 32) * 64;
#pragma unroll
      for (int p = 0; p < 2; ++p)
        lr[p] = reinterpret_cast<const float4*>(ln)[tid + p * 256];
    }
#pragma unroll
    for (int kk = 0; kk < 32; kk += 4) {
      float4 xv[8];
#pragma unroll
      for (int i = 0; i < 8; ++i)
        xv[i] = *reinterpret_cast<const float4*>(&xS[(rg + 16 * i) * 36 + kk]);
#pragma unroll
      for (int q = 0; q < 4; ++q) {
        float4 lv = *reinterpret_cast<const float4*>(&lS[(kk + q) * 64 + c0]);
#pragma unroll
        for (int i = 0; i < 8; ++i) {
          float xs = q == 0 ? xv[i].x : q == 1 ? xv[i].y
                   : q == 2 ? xv[i].z : xv[i].w;
          acc[i][0] += xs * lv.x;
          acc[i][1] += xs * lv.y;
          acc[i][2] += xs * lv.z;
          acc[i][3] += xs * lv.w;
        }
      }
    }
  }
  float* op = tpart + (size_t)blockIdx.y * ((size_t)NROWS * 64);
#pragma unroll
  for (int i = 0; i < 8; ++i)
    *reinterpret_cast<float4*>(op + (rb0 + rg + 16 * i) * 64 + c0) =
        make_float4(acc[i][0], acc[i][1], acc[i][2], acc[i][3]);
}

// ---------------- C2: t = sum_s tpart[s] ----------------
__global__ __launch_bounds__(256) void tt_red(
    const float* __restrict__ tpart, float* __restrict__ t, int splitk) {
  int g = blockIdx.x * 256 + threadIdx.x;  // float4 index, 131072 total
  float4 s = make_float4(0.f, 0.f, 0.f, 0.f);
  const float4* p = reinterpret_cast<const float4*>(tpart) + g;
  for (int i = 0; i < splitk; ++i) {
    float4 v = p[(size_t)i * (NROWS * 16)];
    s.x += v.x; s.y += v.y; s.z += v.z; s.w += v.w;
  }
  reinterpret_cast<float4*>(t)[g] = s;
}

// ---------------- D: y = t @ R + bias (M=8192, N=4096, K=64) ----------------
// 128x128 tile, 512 threads (4x8 thread tile), both operands in LDS.
__global__ __launch_bounds__(512) void tt_tr(
    const float* __restrict__ t, const float* __restrict__ R,
    const float* __restrict__ bias, float* __restrict__ y) {
  __shared__ float tS[128 * 68];  // [row][k] pitch 68
  __shared__ float rS[64 * 128];  // [k][col]
  int tid = threadIdx.x;
  long rb0 = (long)blockIdx.y * 128;
  int cb0 = blockIdx.x * 128;

#pragma unroll
  for (int p = 0; p < 4; ++p) {
    int f = tid + p * 512;
    int row = f >> 4, kq = f & 15;
    *reinterpret_cast<float4*>(&tS[row * 68 + kq * 4]) =
        *reinterpret_cast<const float4*>(t + (rb0 + row) * 64 + kq * 4);
  }
#pragma unroll
  for (int p = 0; p < 4; ++p) {
    int f = tid + p * 512;
    int k = f >> 5, c4 = f & 31;
    *reinterpret_cast<float4*>(&rS[k * 128 + c4 * 4]) =
        *reinterpret_cast<const float4*>(R + (size_t)k * OUT_F + cb0 + c4 * 4);
  }
  __syncthreads();

  int cg = tid & 15, rg = tid >> 4;  // rg 0..31
  int r0 = rg * 4;
  int ca = cg * 4, cb = 64 + cg * 4;
  float acc[4][8] = {};
#pragma unroll
  for (int k = 0; k < 64; k += 4) {
    float4 tv[4];
#pragma unroll
    for (int i = 0; i < 4; ++i)
      tv[i] = *reinterpret_cast<const float4*>(&tS[(r0 + i) * 68 + k]);
#pragma unroll
    for (int q = 0; q < 4; ++q) {
      float4 ra = *reinterpret_cast<const float4*>(&rS[(k + q) * 128 + ca]);
      float4 rb = *reinterpret_cast<const float4*>(&rS[(k + q) * 128 + cb]);
#pragma unroll
      for (int i = 0; i < 4; ++i) {
        float ts = q == 0 ? tv[i].x : q == 1 ? tv[i].y
                 : q == 2 ? tv[i].z : tv[i].w;
        acc[i][0] += ts * ra.x; acc[i][1] += ts * ra.y;
        acc[i][2] += ts * ra.z; acc[i][3] += ts * ra.w;
        acc[i][4] += ts * rb.x; acc[i][5] += ts * rb.y;
        acc[i][6] += ts * rb.z; acc[i][7] += ts * rb.w;
      }
    }
  }
  float4 b0 = *reinterpret_cast<const float4*>(bias + cb0 + ca);
  float4 b1 = *reinterpret_cast<const float4*>(bias + cb0 + cb);
#pragma unroll
  for (int i = 0; i < 4; ++i) {
    float* yp = y + (rb0 + r0 + i) * (long)OUT_F + cb0;
    *reinterpret_cast<float4*>(yp + ca) = make_float4(
        acc[i][0] + b0.x, acc[i][1] + b0.y, acc[i][2] + b0.z, acc[i][3] + b0.w);
    *reinterpret_cast<float4*>(yp + cb) = make_float4(
        acc[i][4] + b1.x, acc[i][5] + b1.y, acc[i][6] + b1.z, acc[i][7] + b1.w);
  }
}

extern "C" void kernel_launch(void* const* d_in, const int* in_sizes, int n_in,
                              void* d_out, int out_size, void* d_ws,
                              size_t ws_size, hipStream_t stream) {
  (void)in_sizes; (void)n_in; (void)out_size;
  const float* x    = (const float*)d_in[0];
  const float* f0   = (const float*)d_in[1];
  const float* f1   = (const float*)d_in[2];
  const float* f2   = (const float*)d_in[3];
  const float* f3   = (const float*)d_in[4];
  const float* f4   = (const float*)d_in[5];
  const float* f5   = (const float*)d_in[6];
  const float* bias = (const float*)d_in[7];
  float* y = (float*)d_out;

  float* ws = (float*)d_ws;
  float* L     = ws;                 // 262144
  float* R     = ws + 262144;        // 262144
  float* G     = ws + 524288;        // 16384
  float* H     = ws + 540672;        // 16384
  float* t     = ws + 557056;        // 524288
  float* tpart = ws + 1081344;       // splitk * 524288

  int splitk = 16;
  while (splitk > 1 &&
         (size_t)(1081344 + (size_t)splitk * 524288) * 4 > ws_size)
    splitk >>= 1;

  tt_p1<<<128, 256, 0, stream>>>(f0, f1, f4, f5, G, H);
  tt_p2<<<2048, 256, 0, stream>>>(f2, f3, G, H, L, R);

  int KC = 4096 / splitk;
  if (splitk > 1) {
    tt_xl<<<dim3(64, splitk), 256, 0, stream>>>(x, L, tpart, KC);
    tt_red<<<512, 256, 0, stream>>>(tpart, t, splitk);
  } else {
    tt_xl<<<dim3(64, 1), 256, 0, stream>>>(x, L, t, 4096);
  }

  tt_tr<<<dim3(32, 64), 512, 0, stream>>>(t, R, bias, y);
}

// Round 5
// 354.113 us; speedup vs baseline: 1.1977x; 1.0554x over previous
//
#include <hip/hip_runtime.h>

#define IN_F 4096
#define OUT_F 4096
#define NROWS 8192

typedef __attribute__((ext_vector_type(8))) short short8;
typedef __attribute__((ext_vector_type(4))) float f32x4;
typedef unsigned short ushort_t;

// truncating bf16 split: v ~= hi + lo, each bf16 (16-bit stored as ushort)
__device__ __forceinline__ ushort_t bf_hi(float v) {
  return (ushort_t)(__float_as_uint(v) >> 16);
}
__device__ __forceinline__ ushort_t bf_lo(float v) {
  float h = __uint_as_float(__float_as_uint(v) & 0xFFFF0000u);
  return (ushort_t)(__float_as_uint(v - h) >> 16);
}

// ---------------- P1: G = f0*f1 [256x64], H = f4*f5 [64x256] ----------------
__global__ __launch_bounds__(256) void tt_p1(
    const float* __restrict__ f0, const float* __restrict__ f1,
    const float* __restrict__ f4, const float* __restrict__ f5,
    float* __restrict__ G, float* __restrict__ H) {
  int g = blockIdx.x * 256 + threadIdx.x;  // 32768 total
  if (g < 16384) {
    int i12 = g >> 6, r2 = g & 63;
    int i1 = i12 >> 4, i2 = i12 & 15;
    const float* a = f0 + i1 * 64;
    const float* b = f1 + i2 * 64 + r2;
    float s = 0.f;
#pragma unroll
    for (int r1 = 0; r1 < 64; ++r1) s += a[r1] * b[r1 * 1024];
    G[g] = s;
  } else {
    int h = g - 16384;
    int r4 = h >> 8, i56 = h & 255;
    int i5 = i56 >> 4, i6 = i56 & 15;
    const float* a = f4 + r4 * 1024 + i5 * 64;
    const float* b = f5 + i6;
    float s = 0.f;
#pragma unroll
    for (int r5 = 0; r5 < 64; ++r5) s += a[r5] * b[r5 * 16];
    H[h] = s;
  }
}

// ------- P2: LT[64][4096] = (G*f2)^T, RT[4096][64] = (f3*H)^T, bf16 pairs ---
__global__ __launch_bounds__(256) void tt_p2(
    const float* __restrict__ f2, const float* __restrict__ f3,
    const float* __restrict__ G, const float* __restrict__ H,
    ushort_t* __restrict__ LT_hi, ushort_t* __restrict__ LT_lo,
    ushort_t* __restrict__ RT_hi, ushort_t* __restrict__ RT_lo) {
  int g = blockIdx.x * 256 + threadIdx.x;  // 524288 total
  if (g < 262144) {
    // L[row][r3] with row = k-index; store transposed LT[r3][row]
    int r3 = g >> 12, row = g & 4095;
    int i12 = row >> 4, i3 = row & 15;
    const float* a = G + i12 * 64;
    const float* b = f2 + i3 * 64 + r3;
    float s = 0.f;
#pragma unroll
    for (int r2 = 0; r2 < 64; ++r2) s += a[r2] * b[r2 * 1024];
    LT_hi[g] = bf_hi(s);
    LT_lo[g] = bf_lo(s);
  } else {
    // R[r3][col]; store transposed RT[col][r3]
    int h = g - 262144;
    int col = h >> 6, r3 = h & 63;
    int i4 = col >> 8, i56 = col & 255;
    const float* a = f3 + r3 * 1024 + i4 * 64;
    const float* b = H + i56;
    float s = 0.f;
#pragma unroll
    for (int r4 = 0; r4 < 64; ++r4) s += a[r4] * b[r4 * 256];
    RT_hi[h] = bf_hi(s);
    RT_lo[h] = bf_lo(s);
  }
}

// ---------------- C: tpart = x @ L  (M=8192, N=64, split-K, MFMA) ----------
// 256 thr = 4 waves; wave owns 32 rows x 64 cols. No LDS. A from x (HBM,
// in-register bf16 split), B from LT (L2-resident bf16 pairs).
__global__ __launch_bounds__(256) void tt_xl(
    const float* __restrict__ x, const ushort_t* __restrict__ LT_hi,
    const ushort_t* __restrict__ LT_lo, float* __restrict__ tpart, int KC) {
  int tid = threadIdx.x;
  int lane = tid & 63, w = tid >> 6;
  int lr = lane & 15, lk = lane >> 4;
  long rb0 = (long)blockIdx.x * 128 + w * 32;
  int k0 = blockIdx.y * KC;
  int nks = KC >> 5;

  f32x4 acc[2][4] = {};

  for (int ks = 0; ks < nks; ++ks) {
    int ka = k0 + ks * 32 + lk * 8;
    short8 ahi[2], alo[2];
#pragma unroll
    for (int m = 0; m < 2; ++m) {
      const float* xp = x + (rb0 + 16 * m + lr) * IN_F + ka;
      float4 v0 = *reinterpret_cast<const float4*>(xp);
      float4 v1 = *reinterpret_cast<const float4*>(xp + 4);
      float vv[8] = {v0.x, v0.y, v0.z, v0.w, v1.x, v1.y, v1.z, v1.w};
#pragma unroll
      for (int j = 0; j < 8; ++j) {
        ahi[m][j] = (short)bf_hi(vv[j]);
        alo[m][j] = (short)bf_lo(vv[j]);
      }
    }
#pragma unroll
    for (int n = 0; n < 4; ++n) {
      int col = 16 * n + lr;
      short8 bhi = *reinterpret_cast<const short8*>(LT_hi + (size_t)col * 4096 + ka);
      short8 blo = *reinterpret_cast<const short8*>(LT_lo + (size_t)col * 4096 + ka);
#pragma unroll
      for (int m = 0; m < 2; ++m) {
        acc[m][n] = __builtin_amdgcn_mfma_f32_16x16x32_bf16(ahi[m], bhi, acc[m][n], 0, 0, 0);
        acc[m][n] = __builtin_amdgcn_mfma_f32_16x16x32_bf16(ahi[m], blo, acc[m][n], 0, 0, 0);
        acc[m][n] = __builtin_amdgcn_mfma_f32_16x16x32_bf16(alo[m], bhi, acc[m][n], 0, 0, 0);
      }
    }
  }

  float* op = tpart + (size_t)blockIdx.y * ((size_t)NROWS * 64);
#pragma unroll
  for (int m = 0; m < 2; ++m)
#pragma unroll
    for (int n = 0; n < 4; ++n)
#pragma unroll
      for (int r = 0; r < 4; ++r) {
        long row = rb0 + 16 * m + 4 * lk + r;
        op[row * 64 + 16 * n + lr] = acc[m][n][r];
      }
}

// ---------------- C2: t = sum_s tpart[s] -> bf16 pair ----------------
__global__ __launch_bounds__(256) void tt_red(
    const float* __restrict__ tpart, ushort_t* __restrict__ t_hi,
    ushort_t* __restrict__ t_lo, int splitk) {
  int g = blockIdx.x * 256 + threadIdx.x;  // float4 index, 131072 total
  float4 s = make_float4(0.f, 0.f, 0.f, 0.f);
  const float4* p = reinterpret_cast<const float4*>(tpart) + g;
  for (int i = 0; i < splitk; ++i) {
    float4 v = p[(size_t)i * (NROWS * 16)];
    s.x += v.x; s.y += v.y; s.z += v.z; s.w += v.w;
  }
  float vv[4] = {s.x, s.y, s.z, s.w};
  ushort4 hv, lv;
  hv.x = bf_hi(vv[0]); hv.y = bf_hi(vv[1]); hv.z = bf_hi(vv[2]); hv.w = bf_hi(vv[3]);
  lv.x = bf_lo(vv[0]); lv.y = bf_lo(vv[1]); lv.z = bf_lo(vv[2]); lv.w = bf_lo(vv[3]);
  *reinterpret_cast<ushort4*>(t_hi + (size_t)g * 4) = hv;
  *reinterpret_cast<ushort4*>(t_lo + (size_t)g * 4) = lv;
}

// ---------------- D: y = t @ R + bias (M=8192, N=4096, K=64, MFMA) ---------
// 256 thr = 4 waves; block tile 64 rows x 256 cols; wave owns 64 rows x 64
// cols. A from t_hi/t_lo, B from RT (both cache-resident). No LDS.
__global__ __launch_bounds__(256) void tt_tr(
    const ushort_t* __restrict__ t_hi, const ushort_t* __restrict__ t_lo,
    const ushort_t* __restrict__ RT_hi, const ushort_t* __restrict__ RT_lo,
    const float* __restrict__ bias, float* __restrict__ y) {
  int tid = threadIdx.x;
  int lane = tid & 63, w = tid >> 6;
  int lr = lane & 15, lk = lane >> 4;
  long rb0 = (long)blockIdx.y * 64;
  int cb0 = blockIdx.x * 256 + w * 64;

  f32x4 acc[4][4] = {};

#pragma unroll
  for (int ks = 0; ks < 2; ++ks) {
    int ka = ks * 32 + lk * 8;
    short8 ahi[4], alo[4];
#pragma unroll
    for (int m = 0; m < 4; ++m) {
      size_t off = (size_t)(rb0 + 16 * m + lr) * 64 + ka;
      ahi[m] = *reinterpret_cast<const short8*>(t_hi + off);
      alo[m] = *reinterpret_cast<const short8*>(t_lo + off);
    }
#pragma unroll
    for (int n = 0; n < 4; ++n) {
      size_t off = (size_t)(cb0 + 16 * n + lr) * 64 + ka;
      short8 bhi = *reinterpret_cast<const short8*>(RT_hi + off);
      short8 blo = *reinterpret_cast<const short8*>(RT_lo + off);
#pragma unroll
      for (int m = 0; m < 4; ++m) {
        acc[m][n] = __builtin_amdgcn_mfma_f32_16x16x32_bf16(ahi[m], bhi, acc[m][n], 0, 0, 0);
        acc[m][n] = __builtin_amdgcn_mfma_f32_16x16x32_bf16(ahi[m], blo, acc[m][n], 0, 0, 0);
        acc[m][n] = __builtin_amdgcn_mfma_f32_16x16x32_bf16(alo[m], bhi, acc[m][n], 0, 0, 0);
      }
    }
  }

#pragma unroll
  for (int n = 0; n < 4; ++n) {
    float bv = bias[cb0 + 16 * n + lr];
#pragma unroll
    for (int m = 0; m < 4; ++m)
#pragma unroll
      for (int r = 0; r < 4; ++r) {
        long row = rb0 + 16 * m + 4 * lk + r;
        y[row * (long)OUT_F + cb0 + 16 * n + lr] = acc[m][n][r] + bv;
      }
  }
}

extern "C" void kernel_launch(void* const* d_in, const int* in_sizes, int n_in,
                              void* d_out, int out_size, void* d_ws,
                              size_t ws_size, hipStream_t stream) {
  (void)in_sizes; (void)n_in; (void)out_size;
  const float* x    = (const float*)d_in[0];
  const float* f0   = (const float*)d_in[1];
  const float* f1   = (const float*)d_in[2];
  const float* f2   = (const float*)d_in[3];
  const float* f3   = (const float*)d_in[4];
  const float* f4   = (const float*)d_in[5];
  const float* f5   = (const float*)d_in[6];
  const float* bias = (const float*)d_in[7];
  float* y = (float*)d_out;

  // workspace layout
  float* G = (float*)d_ws;                     // 16384 f  (64 KB)
  float* H = G + 16384;                        // 16384 f  (64 KB)
  ushort_t* LT_hi = (ushort_t*)(H + 16384);    // 262144 ush (512 KB)
  ushort_t* LT_lo = LT_hi + 262144;
  ushort_t* RT_hi = LT_lo + 262144;
  ushort_t* RT_lo = RT_hi + 262144;
  ushort_t* t_hi  = RT_lo + 262144;            // 524288 ush (1 MB)
  ushort_t* t_lo  = t_hi + 524288;
  float* tpart = (float*)(t_lo + 524288);      // splitk * 524288 f

  int splitk = 16;
  while (splitk > 1 &&
         (size_t)4325376 + (size_t)splitk * 2097152 > ws_size)
    splitk >>= 1;
  int KC = 4096 / splitk;

  tt_p1<<<128, 256, 0, stream>>>(f0, f1, f4, f5, G, H);
  tt_p2<<<2048, 256, 0, stream>>>(f2, f3, G, H, LT_hi, LT_lo, RT_hi, RT_lo);
  tt_xl<<<dim3(64, splitk), 256, 0, stream>>>(x, LT_hi, LT_lo, tpart, KC);
  tt_red<<<512, 256, 0, stream>>>(tpart, t_hi, t_lo, splitk);
  tt_tr<<<dim3(16, 128), 256, 0, stream>>>(t_hi, t_lo, RT_hi, RT_lo, bias, y);
}

// Round 7
// 322.142 us; speedup vs baseline: 1.3165x; 1.0992x over previous
//
#include <hip/hip_runtime.h>

#define IN_F 4096
#define OUT_F 4096
#define NROWS 8192

typedef __attribute__((ext_vector_type(8))) short short8;
typedef __attribute__((ext_vector_type(4))) float f32x4;
typedef unsigned short ushort_t;

// truncating bf16 split: v ~= hi + lo, each bf16 (16-bit stored as ushort)
__device__ __forceinline__ ushort_t bf_hi(float v) {
  return (ushort_t)(__float_as_uint(v) >> 16);
}
__device__ __forceinline__ ushort_t bf_lo(float v) {
  float h = __uint_as_float(__float_as_uint(v) & 0xFFFF0000u);
  return (ushort_t)(__float_as_uint(v - h) >> 16);
}

// ---------------- P1: G = f0*f1 [256x64], H = f4*f5 [64x256] ----------------
__global__ __launch_bounds__(256) void tt_p1(
    const float* __restrict__ f0, const float* __restrict__ f1,
    const float* __restrict__ f4, const float* __restrict__ f5,
    float* __restrict__ G, float* __restrict__ H) {
  int g = blockIdx.x * 256 + threadIdx.x;  // 32768 total
  if (g < 16384) {
    int i12 = g >> 6, r2 = g & 63;
    int i1 = i12 >> 4, i2 = i12 & 15;
    const float* a = f0 + i1 * 64;
    const float* b = f1 + i2 * 64 + r2;
    float s = 0.f;
#pragma unroll
    for (int r1 = 0; r1 < 64; ++r1) s += a[r1] * b[r1 * 1024];
    G[g] = s;
  } else {
    int h = g - 16384;
    int r4 = h >> 8, i56 = h & 255;
    int i5 = i56 >> 4, i6 = i56 & 15;
    const float* a = f4 + r4 * 1024 + i5 * 64;
    const float* b = f5 + i6;
    float s = 0.f;
#pragma unroll
    for (int r5 = 0; r5 < 64; ++r5) s += a[r5] * b[r5 * 16];
    H[h] = s;
  }
}

// ------- P2: LT2 k-tiled [512][64][16] = (G*f2)^T, RT[4096][64] bf16 pairs --
// L-part: thread (row=k wave-uniform group, r3 lane-fast) -> f2 reads
// coalesced, G broadcast. R-part: (r3 wave-uniform, col lane-fast) -> f3
// broadcast, H reads coalesced.
__global__ __launch_bounds__(256) void tt_p2(
    const float* __restrict__ f2, const float* __restrict__ f3,
    const float* __restrict__ G, const float* __restrict__ H,
    ushort_t* __restrict__ LT2,
    ushort_t* __restrict__ RT_hi, ushort_t* __restrict__ RT_lo) {
  int g = blockIdx.x * 256 + threadIdx.x;  // 524288 total
  if (g < 262144) {
    int r3 = g & 63, row = g >> 6;  // row = k index
    int i12 = row >> 4, i3 = row & 15;
    const float* a = G + i12 * 64;
    const float* b = f2 + i3 * 64 + r3;
    float s = 0.f;
#pragma unroll
    for (int r2 = 0; r2 < 64; ++r2) s += a[r2] * b[r2 * 1024];
    ushort_t* p = LT2 + ((size_t)((row >> 3) * 64 + r3) * 16 + (row & 7));
    p[0] = bf_hi(s);
    p[8] = bf_lo(s);
  } else {
    int h = g - 262144;
    int r3 = h >> 12, col = h & 4095;
    int i4 = col >> 8, i56 = col & 255;
    const float* a = f3 + r3 * 1024 + i4 * 64;
    const float* b = H + i56;
    float s = 0.f;
#pragma unroll
    for (int r4 = 0; r4 < 64; ++r4) s += a[r4] * b[r4 * 256];
    RT_hi[(size_t)col * 64 + r3] = bf_hi(s);
    RT_lo[(size_t)col * 64 + r3] = bf_lo(s);
  }
}

// ---------------- C: tpart = x @ L  (M=8192, N=64, split-K, MFMA) ----------
// 256 thr = 4 waves; wave owns 32 rows x 64 cols. No LDS. A from x (HBM,
// register double-buffer + in-register bf16 split), B from k-tiled LT2
// (L2-resident, 4x512B contiguous segments per load instruction).
__global__ __launch_bounds__(256) void tt_xl(
    const float* __restrict__ x, const ushort_t* __restrict__ LT2,
    float* __restrict__ tpart, int KC) {
  int tid = threadIdx.x;
  int lane = tid & 63, w = tid >> 6;
  int lr = lane & 15, lk = lane >> 4;
  long rb0 = (long)blockIdx.x * 128 + w * 32;
  int k0 = blockIdx.y * KC;
  int nks = KC >> 5;

  f32x4 acc[2][4] = {};
  float4 xr[2][2];

  // prologue: load A(ks=0)
#pragma unroll
  for (int m = 0; m < 2; ++m) {
    const float* xp = x + (rb0 + 16 * m + lr) * IN_F + k0 + lk * 8;
    xr[m][0] = *reinterpret_cast<const float4*>(xp);
    xr[m][1] = *reinterpret_cast<const float4*>(xp + 4);
  }

  for (int ks = 0; ks < nks; ++ks) {
    // convert current A to bf16 pairs
    short8 ahi[2], alo[2];
#pragma unroll
    for (int m = 0; m < 2; ++m) {
      float vv[8] = {xr[m][0].x, xr[m][0].y, xr[m][0].z, xr[m][0].w,
                     xr[m][1].x, xr[m][1].y, xr[m][1].z, xr[m][1].w};
#pragma unroll
      for (int j = 0; j < 8; ++j) {
        ahi[m][j] = (short)bf_hi(vv[j]);
        alo[m][j] = (short)bf_lo(vv[j]);
      }
    }
    // B loads: kb = k/8 tile index; contiguous across lr
    int kb = (k0 >> 3) + ks * 4 + lk;
    short8 bhi[4], blo[4];
#pragma unroll
    for (int n = 0; n < 4; ++n) {
      const ushort_t* bp = LT2 + ((size_t)kb * 64 + 16 * n + lr) * 16;
      bhi[n] = *reinterpret_cast<const short8*>(bp);
      blo[n] = *reinterpret_cast<const short8*>(bp + 8);
    }
    // prefetch next A
    if (ks + 1 < nks) {
#pragma unroll
      for (int m = 0; m < 2; ++m) {
        const float* xp =
            x + (rb0 + 16 * m + lr) * IN_F + k0 + (ks + 1) * 32 + lk * 8;
        xr[m][0] = *reinterpret_cast<const float4*>(xp);
        xr[m][1] = *reinterpret_cast<const float4*>(xp + 4);
      }
    }
#pragma unroll
    for (int n = 0; n < 4; ++n)
#pragma unroll
      for (int m = 0; m < 2; ++m) {
        acc[m][n] = __builtin_amdgcn_mfma_f32_16x16x32_bf16(ahi[m], bhi[n], acc[m][n], 0, 0, 0);
        acc[m][n] = __builtin_amdgcn_mfma_f32_16x16x32_bf16(ahi[m], blo[n], acc[m][n], 0, 0, 0);
        acc[m][n] = __builtin_amdgcn_mfma_f32_16x16x32_bf16(alo[m], bhi[n], acc[m][n], 0, 0, 0);
      }
  }

  float* op = tpart + (size_t)blockIdx.y * ((size_t)NROWS * 64);
#pragma unroll
  for (int m = 0; m < 2; ++m)
#pragma unroll
    for (int n = 0; n < 4; ++n)
#pragma unroll
      for (int r = 0; r < 4; ++r) {
        long row = rb0 + 16 * m + 4 * lk + r;
        op[row * 64 + 16 * n + lr] = acc[m][n][r];
      }
}

// ---------------- C2: t = sum_s tpart[s] -> bf16 pair ----------------
__global__ __launch_bounds__(256) void tt_red(
    const float* __restrict__ tpart, ushort_t* __restrict__ t_hi,
    ushort_t* __restrict__ t_lo, int splitk) {
  int g = blockIdx.x * 256 + threadIdx.x;  // float4 index, 131072 total
  float4 s = make_float4(0.f, 0.f, 0.f, 0.f);
  const float4* p = reinterpret_cast<const float4*>(tpart) + g;
  for (int i = 0; i < splitk; ++i) {
    float4 v = p[(size_t)i * (NROWS * 16)];
    s.x += v.x; s.y += v.y; s.z += v.z; s.w += v.w;
  }
  float vv[4] = {s.x, s.y, s.z, s.w};
  ushort4 hv, lv;
  hv.x = bf_hi(vv[0]); hv.y = bf_hi(vv[1]); hv.z = bf_hi(vv[2]); hv.w = bf_hi(vv[3]);
  lv.x = bf_lo(vv[0]); lv.y = bf_lo(vv[1]); lv.z = bf_lo(vv[2]); lv.w = bf_lo(vv[3]);
  *reinterpret_cast<ushort4*>(t_hi + (size_t)g * 4) = hv;
  *reinterpret_cast<ushort4*>(t_lo + (size_t)g * 4) = lv;
}

// ---------------- D: y = t @ R + bias (M=8192, N=4096, K=64, MFMA) ---------
// 256 thr = 4 waves; block tile 64 rows x 256 cols; wave owns 64 rows x 64
// cols. A from t_hi/t_lo, B from RT (both cache-resident). No LDS.
__global__ __launch_bounds__(256) void tt_tr(
    const ushort_t* __restrict__ t_hi, const ushort_t* __restrict__ t_lo,
    const ushort_t* __restrict__ RT_hi, const ushort_t* __restrict__ RT_lo,
    const float* __restrict__ bias, float* __restrict__ y) {
  int tid = threadIdx.x;
  int lane = tid & 63, w = tid >> 6;
  int lr = lane & 15, lk = lane >> 4;
  long rb0 = (long)blockIdx.y * 64;
  int cb0 = blockIdx.x * 256 + w * 64;

  f32x4 acc[4][4] = {};

#pragma unroll
  for (int ks = 0; ks < 2; ++ks) {
    int ka = ks * 32 + lk * 8;
    short8 ahi[4], alo[4];
#pragma unroll
    for (int m = 0; m < 4; ++m) {
      size_t off = (size_t)(rb0 + 16 * m + lr) * 64 + ka;
      ahi[m] = *reinterpret_cast<const short8*>(t_hi + off);
      alo[m] = *reinterpret_cast<const short8*>(t_lo + off);
    }
#pragma unroll
    for (int n = 0; n < 4; ++n) {
      size_t off = (size_t)(cb0 + 16 * n + lr) * 64 + ka;
      short8 bhi = *reinterpret_cast<const short8*>(RT_hi + off);
      short8 blo = *reinterpret_cast<const short8*>(RT_lo + off);
#pragma unroll
      for (int m = 0; m < 4; ++m) {
        acc[m][n] = __builtin_amdgcn_mfma_f32_16x16x32_bf16(ahi[m], bhi, acc[m][n], 0, 0, 0);
        acc[m][n] = __builtin_amdgcn_mfma_f32_16x16x32_bf16(ahi[m], blo, acc[m][n], 0, 0, 0);
        acc[m][n] = __builtin_amdgcn_mfma_f32_16x16x32_bf16(alo[m], bhi, acc[m][n], 0, 0, 0);
      }
    }
  }

#pragma unroll
  for (int n = 0; n < 4; ++n) {
    float bv = bias[cb0 + 16 * n + lr];
#pragma unroll
    for (int m = 0; m < 4; ++m)
#pragma unroll
      for (int r = 0; r < 4; ++r) {
        long row = rb0 + 16 * m + 4 * lk + r;
        y[row * (long)OUT_F + cb0 + 16 * n + lr] = acc[m][n][r] + bv;
      }
  }
}

extern "C" void kernel_launch(void* const* d_in, const int* in_sizes, int n_in,
                              void* d_out, int out_size, void* d_ws,
                              size_t ws_size, hipStream_t stream) {
  (void)in_sizes; (void)n_in; (void)out_size;
  const float* x    = (const float*)d_in[0];
  const float* f0   = (const float*)d_in[1];
  const float* f1   = (const float*)d_in[2];
  const float* f2   = (const float*)d_in[3];
  const float* f3   = (const float*)d_in[4];
  const float* f4   = (const float*)d_in[5];
  const float* f5   = (const float*)d_in[6];
  const float* bias = (const float*)d_in[7];
  float* y = (float*)d_out;

  // workspace layout
  float* G = (float*)d_ws;                     // 16384 f  (64 KB)
  float* H = G + 16384;                        // 16384 f  (64 KB)
  ushort_t* LT2   = (ushort_t*)(H + 16384);    // 524288 ush (1 MB), k-tiled
  ushort_t* RT_hi = LT2 + 524288;              // 262144 ush (512 KB)
  ushort_t* RT_lo = RT_hi + 262144;
  ushort_t* t_hi  = RT_lo + 262144;            // 524288 ush (1 MB)
  ushort_t* t_lo  = t_hi + 524288;
  float* tpart = (float*)(t_lo + 524288);      // splitk * 524288 f

  int splitk = 16;
  while (splitk > 1 &&
         (size_t)4325376 + (size_t)splitk * 2097152 > ws_size)
    splitk >>= 1;
  int KC = 4096 / splitk;

  tt_p1<<<128, 256, 0, stream>>>(f0, f1, f4, f5, G, H);
  tt_p2<<<2048, 256, 0, stream>>>(f2, f3, G, H, LT2, RT_hi, RT_lo);
  tt_xl<<<dim3(64, splitk), 256, 0, stream>>>(x, LT2, tpart, KC);
  tt_red<<<512, 256, 0, stream>>>(tpart, t_hi, t_lo, splitk);
  tt_tr<<<dim3(16, 128), 256, 0, stream>>>(t_hi, t_lo, RT_hi, RT_lo, bias, y);
}